// Round 11
// baseline (89.898 us; speedup 1.0000x reference)
//
#include <hip/hip_runtime.h>
#include <hip/hip_bf16.h>

#define NROWS 8192
#define DDIM  512
#define NS    64
#define KK    8
#define HH    240
#define BK    64     // K-tile per barrier step
#define LDT2  72     // staging pitch, bf16 elems (64 + 8 pad; 144 B = 16B-aligned rows)
#define SP2   72     // samp pitch, bf16 elems (64 + 8 pad)
#define BUFSZ (64 * LDT2)          // one A or B tile, ushort elems

typedef __attribute__((ext_vector_type(8))) short bf16x8;
typedef __attribute__((ext_vector_type(4))) float f32x4;
typedef __attribute__((ext_vector_type(2))) float f32x2;

// packed fp32x2 -> bf16x2 (RNE), lowers to v_cvt_pk_bf16_f32
__device__ inline unsigned cvt2u(float a, float b) {
    __hip_bfloat162 h = __float22bfloat162_rn(make_float2(a, b));
    unsigned u;
    __builtin_memcpy(&u, &h, sizeof(u));
    return u;
}

// ---------------------------------------------------------------------------
// Kernel 0: pack W1 (122880 f) and Th (262144 f) to bf16.
// ---------------------------------------------------------------------------
__global__ __launch_bounds__(256)
void pack_kernel(const float* __restrict__ W1, const float* __restrict__ Th,
                 ushort* __restrict__ W1b, ushort* __restrict__ Thb)
{
    int i = (blockIdx.x * 256 + threadIdx.x) * 4;
    if (i < 122880) {
        float4 v = *(const float4*)(W1 + i);
        *(uint2*)(W1b + i) = make_uint2(cvt2u(v.x, v.y), cvt2u(v.z, v.w));
    } else {
        int j = i - 122880;
        float4 v = *(const float4*)(Th + j);
        *(uint2*)(Thb + j) = make_uint2(cvt2u(v.x, v.y), cvt2u(v.z, v.w));
    }
}

// ---------------------------------------------------------------------------
// Main fused kernel:
//  phase 1: samp64x64 = bf16(rows) @ Thb^T. BK=64, DOUBLE-BUFFERED staging,
//           ONE barrier per K-step (8 steps vs round-10's 16x2 barriers).
//  phase 2: acc (+noise) -> bf16 samp LDS [64 rows][64 (s,k) cols]
//  phase 3: layer-1 MFMA (A=W1 rows=h, B=samp cols=n; b1 in C-init),
//           relu + packed-W3 fma, fused row reductions.
// grid = (256, 8); block = 256 (4 waves, 2x2 over 64x64).
// __launch_bounds__(256, 4): VGPR cap 128 >= natural ~90 -> no spill.
// Measured law (r4/5/8/9): k>=6 forces VGPR 32-40 -> 0.4-1.3 GB scratch.
// ---------------------------------------------------------------------------
__global__ __launch_bounds__(256, 4)
void proj_mlp_kernel(const float* __restrict__ X,
                     const float* __restrict__ Y,
                     const float* __restrict__ Xn,
                     const ushort* __restrict__ Thb,
                     const ushort* __restrict__ W1b,
                     const float* __restrict__ b1,
                     const float* __restrict__ W3,
                     const float* __restrict__ sig_p,
                     float* __restrict__ sumx,   // [NS][128]
                     float* __restrict__ maxy,   // [NS][128]
                     float* __restrict__ sey)    // [NS][128]
{
    __shared__ __align__(16) ushort smem[4 * BUFSZ];   // 36864 B: A0 B0 A1 B1
    ushort* sl = smem;                 // samp [64][SP2] = 9216 B (aliases A0)

    const int tid  = threadIdx.x;
    const int w    = __builtin_amdgcn_readfirstlane(tid >> 6);
    const int lane = tid & 63;
    const int bx   = blockIdx.x;
    const int by   = blockIdx.y;

    const bool isX = (bx < 128);
    const int  bxl = isX ? bx : (bx - 128);
    const float*  srcA = (isX ? X : Y) + (size_t)bxl * 64 * DDIM;
    const ushort* srcB = Thb + (size_t)by * 64 * DDIM;   // [64 rows][512]

    f32x4 acc[2][2];
#pragma unroll
    for (int m = 0; m < 2; ++m)
#pragma unroll
        for (int n = 0; n < 2; ++n) acc[m][n] = (f32x4){0.f, 0.f, 0.f, 0.f};

    const int wr  = (w >> 1) * 32;
    const int wc  = (w & 1) * 32;
    const int r16 = lane & 15;
    const int hi4 = lane >> 4;
    const int offA = (wr + r16) * LDT2 + hi4 * 8;
    const int offB = (wc + r16) * LDT2 + hi4 * 8;

    // A: 64x64 f32 = 4 float4/thread (row f>>4, col4 f&15)
    // B: 64x64 bf16 = 2 uint4/thread (row f>>3, chunk8 f&7)
    const int ar = tid >> 4, ac = tid & 15;
    const int br = tid >> 3, bc = tid & 7;

    float4 ra[4];
    uint4  rbv[2];

#define LOADA(k0) { _Pragma("unroll") \
    for (int i = 0; i < 4; ++i) \
        ra[i] = *(const float4*)(srcA + (size_t)(ar + i * 16) * DDIM + (k0) + ac * 4); }
#define LOADB(k0) { _Pragma("unroll") \
    for (int i = 0; i < 2; ++i) \
        rbv[i] = *(const uint4*)(srcB + (size_t)(br + i * 32) * DDIM + (k0) + bc * 8); }
#define STORE(buf) { ushort* aw_ = smem + (buf) * 2 * BUFSZ; \
    _Pragma("unroll") \
    for (int i = 0; i < 4; ++i) \
        *(uint2*)(aw_ + (ar + i * 16) * LDT2 + ac * 4) = \
            make_uint2(cvt2u(ra[i].x, ra[i].y), cvt2u(ra[i].z, ra[i].w)); \
    ushort* bw_ = aw_ + BUFSZ; \
    _Pragma("unroll") \
    for (int i = 0; i < 2; ++i) \
        *(uint4*)(bw_ + (br + i * 32) * LDT2 + bc * 8) = rbv[i]; }

    // prologue: tile0 -> buf0; issue tile1 loads
    LOADA(0); LOADB(0);
    STORE(0);
    LOADA(64); LOADB(64);
    __syncthreads();

#pragma unroll 2
    for (int kt = 0; kt < 8; ++kt) {
        const int cur = kt & 1;
        const ushort* aT = smem + cur * 2 * BUFSZ;
        const ushort* bT = aT + BUFSZ;

        bf16x8 af[2][2], bfv[2][2];
#pragma unroll
        for (int ks = 0; ks < 2; ++ks) {
#pragma unroll
            for (int m = 0; m < 2; ++m) {
                af[ks][m]  = *(const bf16x8*)(aT + offA + m * 16 * LDT2 + ks * 32);
                bfv[ks][m] = *(const bf16x8*)(bT + offB + m * 16 * LDT2 + ks * 32);
            }
        }
#pragma unroll
        for (int ks = 0; ks < 2; ++ks)
#pragma unroll
            for (int m = 0; m < 2; ++m)
#pragma unroll
                for (int n = 0; n < 2; ++n)
                    acc[m][n] = __builtin_amdgcn_mfma_f32_16x16x32_bf16(
                        af[ks][m], bfv[ks][n], acc[m][n], 0, 0, 0);

        if (kt < 7) STORE(cur ^ 1);          // regs hold tile kt+1
        if (kt < 6) { LOADA((kt + 2) * BK); LOADB((kt + 2) * BK); }
        __syncthreads();
    }

    // ---- phase 2: acc (+noise) -> bf16 samp LDS -----------------------------
    const float sig = *sig_p;
    const bool addnoise = (sig > 0.f) && isX;
    const int n0g = bxl * 64;

#pragma unroll
    for (int m = 0; m < 2; ++m)
#pragma unroll
        for (int n = 0; n < 2; ++n) {
            const int col  = wc + n * 16 + r16;
            const int rowb = wr + m * 16 + hi4 * 4;
            float v[4];
#pragma unroll
            for (int j = 0; j < 4; ++j) {
                v[j] = acc[m][n][j];
                if (addnoise)
                    v[j] = fmaf(sig, Xn[(size_t)(n0g + rowb + j) * (NS * KK) + by * 64 + col], v[j]);
            }
            unsigned u01 = cvt2u(v[0], v[1]);
            unsigned u23 = cvt2u(v[2], v[3]);
            sl[(rowb + 0) * SP2 + col] = (ushort)u01;
            sl[(rowb + 1) * SP2 + col] = (ushort)(u01 >> 16);
            sl[(rowb + 2) * SP2 + col] = (ushort)u23;
            sl[(rowb + 3) * SP2 + col] = (ushort)(u23 >> 16);
        }
    __syncthreads();

    // ---- phase 3: layer-1 MFMA + fused reductions (2 slices per wave) -------
#pragma unroll 1
    for (int si = 0; si < 2; ++si) {
        const int sloc = w * 2 + si;
        const int s    = by * 8 + sloc;

        bf16x8 bsamp[4];
#pragma unroll
        for (int nt = 0; nt < 4; ++nt) {
            bf16x8 t = {0, 0, 0, 0, 0, 0, 0, 0};
            if (hi4 == 0)
                t = *(const bf16x8*)(sl + (nt * 16 + r16) * SP2 + sloc * 8);
            bsamp[nt] = t;
        }

        const ushort* w1p = W1b + (size_t)s * HH * KK;
        const float*  b1p = b1 + s * HH;
        const float*  w3p = W3 + s * HH;

        f32x2 pn2[4];
#pragma unroll
        for (int nt = 0; nt < 4; ++nt) pn2[nt] = (f32x2){0.f, 0.f};

#pragma unroll 5
        for (int ht = 0; ht < HH / 16; ++ht) {
            bf16x8 aw = {0, 0, 0, 0, 0, 0, 0, 0};
            if (hi4 == 0)
                aw = *(const bf16x8*)(w1p + (ht * 16 + r16) * 8);
            float4 b4 = *(const float4*)(b1p + ht * 16 + hi4 * 4);
            float4 w4 = *(const float4*)(w3p + ht * 16 + hi4 * 4);
            f32x4 z   = (f32x4){b4.x, b4.y, b4.z, b4.w};
            f32x2 w01 = (f32x2){w4.x, w4.y};
            f32x2 w23 = (f32x2){w4.z, w4.w};
            const f32x2 zero2 = (f32x2){0.f, 0.f};
#pragma unroll
            for (int nt = 0; nt < 4; ++nt) {
                f32x4 t = __builtin_amdgcn_mfma_f32_16x16x32_bf16(aw, bsamp[nt], z, 0, 0, 0);
                f32x2 t01 = (f32x2){t[0], t[1]};
                f32x2 t23 = (f32x2){t[2], t[3]};
                t01 = __builtin_elementwise_max(t01, zero2);
                t23 = __builtin_elementwise_max(t23, zero2);
                pn2[nt] = __builtin_elementwise_fma(t01, w01, pn2[nt]);
                pn2[nt] = __builtin_elementwise_fma(t23, w23, pn2[nt]);
            }
        }

        if (isX) {
            float lsum = 0.f;
#pragma unroll
            for (int nt = 0; nt < 4; ++nt) lsum += pn2[nt].x + pn2[nt].y;
#pragma unroll
            for (int off = 1; off < 64; off <<= 1)
                lsum += __shfl_xor(lsum, off);
            if (lane == 0) sumx[s * 128 + bxl] = lsum;
        } else {
            float p[4];
#pragma unroll
            for (int nt = 0; nt < 4; ++nt) {
                f32x2 v = pn2[nt];
                v.x += __shfl_xor(v.x, 16);
                v.y += __shfl_xor(v.y, 16);
                v.x += __shfl_xor(v.x, 32);
                v.y += __shfl_xor(v.y, 32);
                p[nt] = v.x + v.y;
            }
            float M = fmaxf(fmaxf(p[0], p[1]), fmaxf(p[2], p[3]));
            float se = __expf(p[0] - M) + __expf(p[1] - M)
                     + __expf(p[2] - M) + __expf(p[3] - M);
#pragma unroll
            for (int off = 1; off < 16; off <<= 1) {
                float Mo = __shfl_xor(M, off);
                float so = __shfl_xor(se, off);
                float Mm = fmaxf(M, Mo);
                se = se * __expf(M - Mm) + so * __expf(Mo - Mm);
                M = Mm;
            }
            if (lane == 0) {
                maxy[s * 128 + bxl] = M;
                sey[s * 128 + bxl]  = se;
            }
        }
    }
}

// ---------------------------------------------------------------------------
// Final: 256 threads; thread (s, q) covers 32 partials; shfl-combine; wave-0
// reduces 64 slice terms -> scalar.
// ---------------------------------------------------------------------------
__global__ __launch_bounds__(256)
void final_kernel(const float* __restrict__ sumx,
                  const float* __restrict__ maxy,
                  const float* __restrict__ sey,
                  float* __restrict__ out)
{
    __shared__ float term_s[NS];
    const int tid = threadIdx.x;
    const int s = tid >> 2, q = tid & 3;
    const int base = s * 128 + q * 32;

    float sum = 0.f, M = -3.4e38f;
#pragma unroll 8
    for (int i = 0; i < 32; ++i) {
        sum += sumx[base + i];
        M = fmaxf(M, maxy[base + i]);
    }
    float se = 0.f;
#pragma unroll 8
    for (int i = 0; i < 32; ++i)
        se += sey[base + i] * __expf(maxy[base + i] - M);

#pragma unroll
    for (int off = 1; off < 4; off <<= 1) {
        float Mo = __shfl_xor(M, off);
        float so = __shfl_xor(se, off);
        float su = __shfl_xor(sum, off);
        float Mm = fmaxf(M, Mo);
        se = se * __expf(M - Mm) + so * __expf(Mo - Mm);
        M = Mm;
        sum += su;
    }
    if (q == 0)
        term_s[s] = M + logf(se) - logf((float)NROWS) - sum * (1.0f / (float)NROWS);
    __syncthreads();
    if (tid < 64) {
        float v = term_s[tid];
#pragma unroll
        for (int off = 1; off < 64; off <<= 1) v += __shfl_xor(v, off);
        if (tid == 0) out[0] = v * (1.0f / (float)NS);
    }
}

// ---------------------------------------------------------------------------
extern "C" void kernel_launch(void* const* d_in, const int* in_sizes, int n_in,
                              void* d_out, int out_size, void* d_ws, size_t ws_size,
                              hipStream_t stream)
{
    const float* X   = (const float*)d_in[0];
    const float* Y   = (const float*)d_in[1];
    const float* Xn  = (const float*)d_in[2];
    const float* Th  = (const float*)d_in[3];
    const float* W1  = (const float*)d_in[4];
    const float* b1  = (const float*)d_in[5];
    const float* W3  = (const float*)d_in[6];
    // d_in[7] = b3: cancels exactly between mean_x and LSE_y -> unused
    const float* sig = (const float*)d_in[8];

    ushort* W1b  = (ushort*)d_ws;                     // 122880 bf16
    ushort* Thb  = W1b + 122880;                      // 262144 bf16
    float*  sumx = (float*)(Thb + 262144);
    float*  maxy = sumx + NS * 128;
    float*  sey  = maxy + NS * 128;

    pack_kernel<<<(122880 + 262144) / 1024, 256, 0, stream>>>(W1, Th, W1b, Thb);

    dim3 g1(256, 8, 1);
    proj_mlp_kernel<<<g1, 256, 0, stream>>>(X, Y, Xn, Thb, W1b, b1, W3,
                                            sig, sumx, maxy, sey);
    final_kernel<<<1, 256, 0, stream>>>(sumx, maxy, sey, (float*)d_out);
}

// Round 13
// 68.669 us; speedup vs baseline: 1.3091x; 1.3091x over previous
//
#include <hip/hip_runtime.h>
#include <hip/hip_bf16.h>

#define NROWS 8192
#define DDIM  512
#define NS    64
#define KK    8
#define HH    240
#define LDT   40     // staging pitch, f16 elems (32 + 8 pad)
#define SP2   72     // samp pitch, f16 elems (64 + 8 pad)
#define BUF   (64 * LDT)   // one A-or-B tile in ushorts (2560)

typedef __attribute__((ext_vector_type(8))) _Float16 f16x8;
typedef __attribute__((ext_vector_type(4))) _Float16 f16x4;
typedef __attribute__((ext_vector_type(4))) float f32x4;
typedef __attribute__((ext_vector_type(2))) float f32x2;

// packed fp32x2 -> f16x2 (RTZ), lowers to v_cvt_pkrtz_f16_f32 (1 instr)
__device__ inline unsigned pk2u(float a, float b) {
    auto h = __builtin_amdgcn_cvt_pkrtz(a, b);   // __fp16 ext_vector(2)
    unsigned u;
    __builtin_memcpy(&u, &h, sizeof(u));
    return u;
}

// ---------------------------------------------------------------------------
// Kernel 0: pack W1 (122880 f) and Th (262144 f) to f16.
// ---------------------------------------------------------------------------
__global__ __launch_bounds__(256)
void pack_kernel(const float* __restrict__ W1, const float* __restrict__ Th,
                 ushort* __restrict__ W1h, ushort* __restrict__ Thh)
{
    int i = (blockIdx.x * 256 + threadIdx.x) * 4;
    if (i < 122880) {
        float4 v = *(const float4*)(W1 + i);
        *(uint2*)(W1h + i) = make_uint2(pk2u(v.x, v.y), pk2u(v.z, v.w));
    } else {
        int j = i - 122880;
        float4 v = *(const float4*)(Th + j);
        *(uint2*)(Thh + j) = make_uint2(pk2u(v.x, v.y), pk2u(v.z, v.w));
    }
}

// ---------------------------------------------------------------------------
// Main fused kernel (all-f16 operands, fp32 accumulate):
//  phase 1: samp64x64 = f16(rows) @ Thh^T. BK=32, LDS DOUBLE-BUFFER with
//           ONE barrier per K-step (17 barriers vs r10's 33). Register
//           footprint identical to r10 (ra[2]+rbv[1]) -- the 64-VGPR law
//           from r8-r11: any larger staging footprint spills.
//  phase 2: acc (+noise) -> f16 samp LDS [64 rows][64 (s,k) cols]
//  phase 3: layer-1 via mfma_f32_16x16x16f16 (K=16: 2x pad instead of 4x),
//           b1 in C-init, relu + packed-W3 fma, fused row reductions.
// grid = (256, 8); block = 256 (4 waves, 2x2 over 64x64).
// ---------------------------------------------------------------------------
__global__ __launch_bounds__(256, 4)
void proj_mlp_kernel(const float* __restrict__ X,
                     const float* __restrict__ Y,
                     const float* __restrict__ Xn,
                     const ushort* __restrict__ Thh,
                     const ushort* __restrict__ W1h,
                     const float* __restrict__ b1,
                     const float* __restrict__ W3,
                     const float* __restrict__ sig_p,
                     float* __restrict__ sumx,   // [NS][128]
                     float* __restrict__ maxy,   // [NS][128]
                     float* __restrict__ sey)    // [NS][128]
{
    __shared__ __align__(16) ushort smem[4 * BUF];   // 20480 B: {A0,B0},{A1,B1}
    ushort* sl = smem;                 // samp [64][SP2] = 9216 B (aliases buf0)

    const int tid  = threadIdx.x;
    const int w    = __builtin_amdgcn_readfirstlane(tid >> 6);
    const int lane = tid & 63;
    const int bx   = blockIdx.x;
    const int by   = blockIdx.y;

    const bool isX = (bx < 128);
    const int  bxl = isX ? bx : (bx - 128);
    const float*  srcA = (isX ? X : Y) + (size_t)bxl * 64 * DDIM;
    const ushort* srcB = Thh + (size_t)by * 64 * DDIM;   // [64 rows][512]

    f32x4 acc[2][2];
#pragma unroll
    for (int m = 0; m < 2; ++m)
#pragma unroll
        for (int n = 0; n < 2; ++n) acc[m][n] = (f32x4){0.f, 0.f, 0.f, 0.f};

    const int wr  = (w >> 1) * 32;
    const int wc  = (w & 1) * 32;
    const int r16 = lane & 15;
    const int hi4 = lane >> 4;
    const int offA = (wr + r16) * LDT + hi4 * 8;
    const int offB = (wc + r16) * LDT + hi4 * 8;

    // A: 64x32 f32 = 2 float4/thread; B: 64x32 f16 = 1 uint4/thread
    const int arow0 = tid >> 3,  ac4 = tid & 7;
    const int brow  = tid >> 2,  bh  = tid & 3;

    float4 ra[2];
    uint4  rbv;

#define LOADA(k0) { _Pragma("unroll") \
    for (int i = 0; i < 2; ++i) \
        ra[i] = *(const float4*)(srcA + (size_t)(arow0 + i * 32) * DDIM + (k0) + ac4 * 4); }
#define LOADB(k0) \
    rbv = *(const uint4*)(srcB + brow * DDIM + (k0) + bh * 8);
#define STORE(buf) { ushort* aw_ = smem + (buf) * 2 * BUF; \
    _Pragma("unroll") \
    for (int i = 0; i < 2; ++i) \
        *(uint2*)(aw_ + (arow0 + i * 32) * LDT + ac4 * 4) = \
            make_uint2(pk2u(ra[i].x, ra[i].y), pk2u(ra[i].z, ra[i].w)); \
    *(uint4*)(aw_ + BUF + brow * LDT + bh * 8) = rbv; }

    // prologue: tile0 -> buf0; issue tile1 loads
    LOADA(0); LOADB(0);
    STORE(0);
    LOADA(32); LOADB(32);
    __syncthreads();

#pragma unroll 2
    for (int kt = 0; kt < 16; ++kt) {
        const int cur = kt & 1;
        const ushort* aT = smem + cur * 2 * BUF;
        const ushort* bT = aT + BUF;

        f16x8 af[2], bfv[2];
#pragma unroll
        for (int m = 0; m < 2; ++m) {
            af[m]  = *(const f16x8*)(aT + offA + m * 16 * LDT);
            bfv[m] = *(const f16x8*)(bT + offB + m * 16 * LDT);
        }
#pragma unroll
        for (int m = 0; m < 2; ++m)
#pragma unroll
            for (int n = 0; n < 2; ++n)
                acc[m][n] = __builtin_amdgcn_mfma_f32_16x16x32_f16(
                    af[m], bfv[n], acc[m][n], 0, 0, 0);

        if (kt < 15) STORE(cur ^ 1);                 // regs hold tile kt+1
        if (kt < 14) { LOADA((kt + 2) * 32); LOADB((kt + 2) * 32); }
        __syncthreads();
    }

    // ---- phase 2: acc (+noise) -> f16 samp LDS ------------------------------
    const float sig = *sig_p;
    const bool addnoise = (sig > 0.f) && isX;
    const int n0g = bxl * 64;

#pragma unroll
    for (int m = 0; m < 2; ++m)
#pragma unroll
        for (int n = 0; n < 2; ++n) {
            const int col  = wc + n * 16 + r16;
            const int rowb = wr + m * 16 + hi4 * 4;
            float v[4];
#pragma unroll
            for (int j = 0; j < 4; ++j) {
                v[j] = acc[m][n][j];
                if (addnoise)
                    v[j] = fmaf(sig, Xn[(size_t)(n0g + rowb + j) * (NS * KK) + by * 64 + col], v[j]);
            }
            unsigned u01 = pk2u(v[0], v[1]);
            unsigned u23 = pk2u(v[2], v[3]);
            sl[(rowb + 0) * SP2 + col] = (ushort)u01;
            sl[(rowb + 1) * SP2 + col] = (ushort)(u01 >> 16);
            sl[(rowb + 2) * SP2 + col] = (ushort)u23;
            sl[(rowb + 3) * SP2 + col] = (ushort)(u23 >> 16);
        }
    __syncthreads();

    // ---- phase 3: layer-1 16x16x16 f16 MFMA + fused reductions --------------
#pragma unroll 1
    for (int si = 0; si < 2; ++si) {
        const int sloc = w * 2 + si;
        const int s    = by * 8 + sloc;

        // B-frag (samp): lane (r16=n, hi4=kgrp) holds k = hi4*4..+4; k>=8 zero
        f16x4 bsamp[4];
#pragma unroll
        for (int nt = 0; nt < 4; ++nt) {
            f16x4 t = {0, 0, 0, 0};
            if (hi4 < 2)
                t = *(const f16x4*)(sl + (nt * 16 + r16) * SP2 + sloc * 8 + hi4 * 4);
            bsamp[nt] = t;
        }

        const ushort* w1p = W1h + (size_t)s * HH * KK;
        const float*  b1p = b1 + s * HH;
        const float*  w3p = W3 + s * HH;

        f32x2 pn2[4];
#pragma unroll
        for (int nt = 0; nt < 4; ++nt) pn2[nt] = (f32x2){0.f, 0.f};

#pragma unroll 5
        for (int ht = 0; ht < HH / 16; ++ht) {
            f16x4 aw = {0, 0, 0, 0};
            if (hi4 < 2)
                aw = *(const f16x4*)(w1p + (ht * 16 + r16) * 8 + hi4 * 4);
            float4 b4 = *(const float4*)(b1p + ht * 16 + hi4 * 4);
            float4 w4 = *(const float4*)(w3p + ht * 16 + hi4 * 4);
            f32x4 z   = (f32x4){b4.x, b4.y, b4.z, b4.w};
            f32x2 w01 = (f32x2){w4.x, w4.y};
            f32x2 w23 = (f32x2){w4.z, w4.w};
            const f32x2 zero2 = (f32x2){0.f, 0.f};
#pragma unroll
            for (int nt = 0; nt < 4; ++nt) {
                f32x4 t = __builtin_amdgcn_mfma_f32_16x16x16f16(aw, bsamp[nt], z, 0, 0, 0);
                f32x2 t01 = (f32x2){t[0], t[1]};
                f32x2 t23 = (f32x2){t[2], t[3]};
                t01 = __builtin_elementwise_max(t01, zero2);
                t23 = __builtin_elementwise_max(t23, zero2);
                pn2[nt] = __builtin_elementwise_fma(t01, w01, pn2[nt]);
                pn2[nt] = __builtin_elementwise_fma(t23, w23, pn2[nt]);
            }
        }

        if (isX) {
            float lsum = 0.f;
#pragma unroll
            for (int nt = 0; nt < 4; ++nt) lsum += pn2[nt].x + pn2[nt].y;
#pragma unroll
            for (int off = 1; off < 64; off <<= 1)
                lsum += __shfl_xor(lsum, off);
            if (lane == 0) sumx[s * 128 + bxl] = lsum;
        } else {
            float p[4];
#pragma unroll
            for (int nt = 0; nt < 4; ++nt) {
                f32x2 v = pn2[nt];
                v.x += __shfl_xor(v.x, 16);
                v.y += __shfl_xor(v.y, 16);
                v.x += __shfl_xor(v.x, 32);
                v.y += __shfl_xor(v.y, 32);
                p[nt] = v.x + v.y;
            }
            float M = fmaxf(fmaxf(p[0], p[1]), fmaxf(p[2], p[3]));
            float se = __expf(p[0] - M) + __expf(p[1] - M)
                     + __expf(p[2] - M) + __expf(p[3] - M);
#pragma unroll
            for (int off = 1; off < 16; off <<= 1) {
                float Mo = __shfl_xor(M, off);
                float so = __shfl_xor(se, off);
                float Mm = fmaxf(M, Mo);
                se = se * __expf(M - Mm) + so * __expf(Mo - Mm);
                M = Mm;
            }
            if (lane == 0) {
                maxy[s * 128 + bxl] = M;
                sey[s * 128 + bxl]  = se;
            }
        }
    }
}

// ---------------------------------------------------------------------------
// Final: 256 threads; thread (s, q) covers 32 partials; shfl-combine; wave-0
// reduces 64 slice terms -> scalar.
// ---------------------------------------------------------------------------
__global__ __launch_bounds__(256)
void final_kernel(const float* __restrict__ sumx,
                  const float* __restrict__ maxy,
                  const float* __restrict__ sey,
                  float* __restrict__ out)
{
    __shared__ float term_s[NS];
    const int tid = threadIdx.x;
    const int s = tid >> 2, q = tid & 3;
    const int base = s * 128 + q * 32;

    float sum = 0.f, M = -3.4e38f;
#pragma unroll 8
    for (int i = 0; i < 32; ++i) {
        sum += sumx[base + i];
        M = fmaxf(M, maxy[base + i]);
    }
    float se = 0.f;
#pragma unroll 8
    for (int i = 0; i < 32; ++i)
        se += sey[base + i] * __expf(maxy[base + i] - M);

#pragma unroll
    for (int off = 1; off < 4; off <<= 1) {
        float Mo = __shfl_xor(M, off);
        float so = __shfl_xor(se, off);
        float su = __shfl_xor(sum, off);
        float Mm = fmaxf(M, Mo);
        se = se * __expf(M - Mm) + so * __expf(Mo - Mm);
        M = Mm;
        sum += su;
    }
    if (q == 0)
        term_s[s] = M + logf(se) - logf((float)NROWS) - sum * (1.0f / (float)NROWS);
    __syncthreads();
    if (tid < 64) {
        float v = term_s[tid];
#pragma unroll
        for (int off = 1; off < 64; off <<= 1) v += __shfl_xor(v, off);
        if (tid == 0) out[0] = v * (1.0f / (float)NS);
    }
}

// ---------------------------------------------------------------------------
extern "C" void kernel_launch(void* const* d_in, const int* in_sizes, int n_in,
                              void* d_out, int out_size, void* d_ws, size_t ws_size,
                              hipStream_t stream)
{
    const float* X   = (const float*)d_in[0];
    const float* Y   = (const float*)d_in[1];
    const float* Xn  = (const float*)d_in[2];
    const float* Th  = (const float*)d_in[3];
    const float* W1  = (const float*)d_in[4];
    const float* b1  = (const float*)d_in[5];
    const float* W3  = (const float*)d_in[6];
    // d_in[7] = b3: cancels exactly between mean_x and LSE_y -> unused
    const float* sig = (const float*)d_in[8];

    ushort* W1h  = (ushort*)d_ws;                     // 122880 f16
    ushort* Thh  = W1h + 122880;                      // 262144 f16
    float*  sumx = (float*)(Thh + 262144);
    float*  maxy = sumx + NS * 128;
    float*  sey  = maxy + NS * 128;

    pack_kernel<<<(122880 + 262144) / 1024, 256, 0, stream>>>(W1, Th, W1h, Thh);

    dim3 g1(256, 8, 1);
    proj_mlp_kernel<<<g1, 256, 0, stream>>>(X, Y, Xn, Thh, W1h, b1, W3,
                                            sig, sumx, maxy, sey);
    final_kernel<<<1, 256, 0, stream>>>(sumx, maxy, sey, (float*)d_out);
}